// Round 5
// baseline (26.182 us; speedup 1.0000x reference)
//
#include <hip/hip_runtime.h>

#define N_CODONS 65
#define N_AA 24

// codon -> AA table: codon 0 -> AA 0; codons 1..64 -> AAs 3..23 with sizes
// {4,6,2,2,2,2,2,3,2,6,1,2,4,2,6,4,4,1,2,4,3}
__constant__ int c_codon2aa[N_CODONS] = {
    0,
    3,3,3,3,
    4,4,4,4,4,4,
    5,5,
    6,6,
    7,7,
    8,8,
    9,9,
    10,10,10,
    11,11,
    12,12,12,12,12,12,
    13,
    14,14,
    15,15,15,15,
    16,16,
    17,17,17,17,17,17,
    18,18,18,18,
    19,19,19,19,
    20,
    21,21,
    22,22,22,22,
    23,23,23
};

// NSYN_CODON: AA 23 (codons 62..64) and codon 0 have NSYN 0.
__constant__ float c_nsyn[N_CODONS] = {
    0.f,
    4.f,4.f,4.f,4.f,
    6.f,6.f,6.f,6.f,6.f,6.f,
    2.f,2.f,
    2.f,2.f,
    2.f,2.f,
    2.f,2.f,
    2.f,2.f,
    3.f,3.f,3.f,
    2.f,2.f,
    6.f,6.f,6.f,6.f,6.f,6.f,
    1.f,
    2.f,2.f,
    4.f,4.f,4.f,4.f,
    2.f,2.f,
    6.f,6.f,6.f,6.f,6.f,6.f,
    4.f,4.f,4.f,4.f,
    4.f,4.f,4.f,4.f,
    1.f,
    2.f,2.f,
    4.f,4.f,4.f,4.f,
    0.f,0.f,0.f
};

__device__ __forceinline__ float wave_sum64(float v) {
#pragma unroll
    for (int off = 32; off > 0; off >>= 1)
        v += __shfl_xor(v, off, 64);
    return v;
}

__global__ __launch_bounds__(1024)
void rscu_kl_kernel(const int* __restrict__ pred,
                    const int* __restrict__ targ,
                    const int* __restrict__ mask,   // bool promoted to int32 by harness
                    const int* __restrict__ species,
                    const float* __restrict__ ref,
                    float* __restrict__ out,
                    int L, int n_species)
{
    const int b    = blockIdx.x;
    const int tid  = threadIdx.x;
    const int lane = tid & 63;

    // Byte-packed, lane-sliced histograms shared by ALL waves (see r4 notes).
    __shared__ unsigned int h[2][16][N_CODONS];
    __shared__ float pr[N_CODONS];
    __shared__ float tr[N_CODONS];
    __shared__ float aaP[N_AA], aaT[N_AA];

    for (int i = tid; i < 2 * 16 * N_CODONS; i += 1024)
        ((unsigned int*)h)[i] = 0u;
    if (tid < N_AA) { aaP[tid] = 0.f; aaT[tid] = 0.f; }
    __syncthreads();

    // ---- Phase 1: histograms (coalesced int4 loads, branchless) ----
    const int4* p4 = (const int4*)(pred + (size_t)b * L);
    const int4* t4 = (const int4*)(targ + (size_t)b * L);
    const int4* m4 = (const int4*)(mask + (size_t)b * L);
    const int nvec = L >> 2;

    unsigned int* hp = &h[0][lane >> 2][0];
    unsigned int* ht = &h[1][lane >> 2][0];
    const unsigned int inc = 1u << ((lane & 3) * 8);

    for (int i = tid; i < nvec; i += 1024) {
        int4 pv = p4[i];
        int4 tv = t4[i];
        int4 mv = m4[i];
        int bp0 = mv.x ? pv.x : 0;  int bt0 = mv.x ? tv.x : 0;
        int bp1 = mv.y ? pv.y : 0;  int bt1 = mv.y ? tv.y : 0;
        int bp2 = mv.z ? pv.z : 0;  int bt2 = mv.z ? tv.z : 0;
        int bp3 = mv.w ? pv.w : 0;  int bt3 = mv.w ? tv.w : 0;
        atomicAdd(hp + bp0, inc);   atomicAdd(ht + bt0, inc);
        atomicAdd(hp + bp1, inc);   atomicAdd(ht + bt1, inc);
        atomicAdd(hp + bp2, inc);   atomicAdd(ht + bt2, inc);
        atomicAdd(hp + bp3, inc);   atomicAdd(ht + bt3, inc);
    }
    __syncthreads();

    // ---- Phase 2: merge byte-counters, per-AA totals ----
    if (tid < N_CODONS) {
        unsigned int sp = 0u, st = 0u;
#pragma unroll
        for (int g = 0; g < 16; ++g) {
            unsigned int wp = h[0][g][tid];
            unsigned int wt = h[1][g][tid];
            sp += (wp & 0x00FF00FFu) + ((wp >> 8) & 0x00FF00FFu);
            st += (wt & 0x00FF00FFu) + ((wt >> 8) & 0x00FF00FFu);
        }
        float fcp = (float)((sp & 0xFFFFu) + (sp >> 16));
        float fct = (float)((st & 0xFFFFu) + (st >> 16));
        pr[tid] = fcp;
        tr[tid] = fct;
        int a = c_codon2aa[tid];
        atomicAdd(&aaP[a], fcp);
        atomicAdd(&aaT[a], fct);
    }
    __syncthreads();

    // ---- Phase 3: per-codon RSCU + blend with species reference ----
    if (tid < N_CODONS) {
        int sp = species[b];
        float rv = (sp >= 0 && sp < n_species) ? ref[sp * N_CODONS + tid] : 0.f;
        int a = c_codon2aa[tid];
        float nsyn = c_nsyn[tid];
        float totP = aaP[a], totT = aaT[a];
        float rscu_p = (totP > 0.f) ? pr[tid] * nsyn / fmaxf(totP, 1.f) : 0.f;
        float rscu_t = (totT > 0.f) ? tr[tid] * nsyn / fmaxf(totT, 1.f) : 0.f;
        pr[tid] = rscu_p + 1e-8f;
        tr[tid] = 0.7f * rscu_t + 0.3f * rv + 1e-8f;
    }
    __syncthreads();

    // ---- Phase 4: normalize + KL, wave 0 only ----
    if (tid < 64) {
        float pv = pr[tid] + (tid == 0 ? pr[64] : 0.f);
        float tv = tr[tid] + (tid == 0 ? tr[64] : 0.f);
        float psum = wave_sum64(pv);
        float tsum = wave_sum64(tv);
        float inv_ps = 1.f / psum;
        float inv_ts = 1.f / tsum;

        float tn = tr[tid] * inv_ts;
        float pn = pr[tid] * inv_ps;
        float kl = tn * __logf(tn / pn);
        if (tid == 0) {
            float tn2 = tr[64] * inv_ts;
            float pn2 = pr[64] * inv_ps;
            kl += tn2 * __logf(tn2 / pn2);
        }
        kl = wave_sum64(kl);
        if (tid == 0) out[b] = kl;
    }
}

extern "C" void kernel_launch(void* const* d_in, const int* in_sizes, int n_in,
                              void* d_out, int out_size, void* d_ws, size_t ws_size,
                              hipStream_t stream) {
    // DIAGNOSTIC ROUND: launch the identical, idempotent kernel TWICE.
    // dur(this round) - dur(round 4) ~= device time of one kernel, separating
    // fixed graph-replay/launch overhead from device-side work. Both launches
    // compute identical results (kernel re-zeros its LDS and rewrites out),
    // so determinism and correctness are unchanged.
    const int* pred    = (const int*)d_in[0];
    const int* targ    = (const int*)d_in[1];
    const int* species = (const int*)d_in[3];
    const int* mask    = (const int*)d_in[4];
    const float* ref   = (const float*)d_in[5];
    float* out         = (float*)d_out;

    const int B = in_sizes[3];
    const int L = in_sizes[0] / B;
    const int n_species = in_sizes[5] / N_CODONS;

    rscu_kl_kernel<<<dim3(B), dim3(1024), 0, stream>>>(
        pred, targ, mask, species, ref, out, L, n_species);
    rscu_kl_kernel<<<dim3(B), dim3(1024), 0, stream>>>(
        pred, targ, mask, species, ref, out, L, n_species);
}

// Round 6
// 15.628 us; speedup vs baseline: 1.6753x; 1.6753x over previous
//
#include <hip/hip_runtime.h>

#define N_CODONS 65
#define N_AA 24

// codon -> AA: codon 0 -> AA 0; codons 1..64 -> AAs 3..23 with sizes
// {4,6,2,2,2,2,2,3,2,6,1,2,4,2,6,4,4,1,2,4,3}
__constant__ int c_codon2aa[N_CODONS] = {
    0,
    3,3,3,3,
    4,4,4,4,4,4,
    5,5,
    6,6,
    7,7,
    8,8,
    9,9,
    10,10,10,
    11,11,
    12,12,12,12,12,12,
    13,
    14,14,
    15,15,15,15,
    16,16,
    17,17,17,17,17,17,
    18,18,18,18,
    19,19,19,19,
    20,
    21,21,
    22,22,22,22,
    23,23,23
};

// NSYN_CODON: AA 23 (codons 62..64) and codon 0 have NSYN 0.
__constant__ float c_nsyn[N_CODONS] = {
    0.f,
    4.f,4.f,4.f,4.f,
    6.f,6.f,6.f,6.f,6.f,6.f,
    2.f,2.f,
    2.f,2.f,
    2.f,2.f,
    2.f,2.f,
    2.f,2.f,
    3.f,3.f,3.f,
    2.f,2.f,
    6.f,6.f,6.f,6.f,6.f,6.f,
    1.f,
    2.f,2.f,
    4.f,4.f,4.f,4.f,
    2.f,2.f,
    6.f,6.f,6.f,6.f,6.f,6.f,
    4.f,4.f,4.f,4.f,
    4.f,4.f,4.f,4.f,
    1.f,
    2.f,2.f,
    4.f,4.f,4.f,4.f,
    0.f,0.f,0.f
};

// Per-AA codon range (offset, size) for AA sums (AAs 0..2 alias codon 0,
// harmless: no real codon maps there and NSYN=0).
__constant__ int c_off[N_AA] = {0,0,0, 1,5,11,13,15,17,19,21,24,26,32,33,35,39,41,47,51,55,56,58,62};
__constant__ int c_sz [N_AA] = {1,1,1, 4,6,2,2,2,2,2,3,2,6,1,2,4,2,6,4,4,1,2,4,3};

__device__ __forceinline__ float wave_sum64(float v) {
#pragma unroll
    for (int off = 32; off > 0; off >>= 1)
        v += __shfl_xor(v, off, 64);
    return v;
}

__global__ __launch_bounds__(1024)
void rscu_kl_kernel(const int* __restrict__ pred,
                    const int* __restrict__ targ,
                    const int* __restrict__ mask,   // bool promoted to int32 by harness
                    const int* __restrict__ species,
                    const float* __restrict__ ref,
                    float* __restrict__ out,
                    int L, int n_species)
{
    const int b    = blockIdx.x;
    const int tid  = threadIdx.x;
    const int lane = tid & 63;

    // Byte-packed, lane-sliced histograms shared by all waves:
    // word h[which][grp][bin]; lane l adds 1<<(8*(l&3)) into grp=l>>2.
    // Max per byte slot = 16 waves * 8 elems = 128 < 256: no carry.
    // bin 0 = dump slot for masked elements (NSYN[0]=0 -> don't-care).
    __shared__ unsigned int h[2][16][N_CODONS];
    __shared__ float pr[N_CODONS];   // merged raw pred counts
    __shared__ float tr[N_CODONS];   // merged raw targ counts

    // Wave 0 prefetches the species ref row (used only in phase 3).
    float rv = 0.f, rv64 = 0.f;
    if (tid < 64) {
        int sp = species[b];
        if (sp >= 0 && sp < n_species) {
            rv = ref[sp * N_CODONS + tid];
            if (tid == 0) rv64 = ref[sp * N_CODONS + 64];
        }
    }

    for (int i = tid; i < 2 * 16 * N_CODONS; i += 1024)
        ((unsigned int*)h)[i] = 0u;
    __syncthreads();

    // ---- Phase 1: histograms; 8 elems/thread, straight-line, branchless ----
    const size_t rowoff = (size_t)b * L;
    const int4* p4 = (const int4*)(pred + rowoff);
    const int4* t4 = (const int4*)(targ + rowoff);
    const int4* m4 = (const int4*)(mask + rowoff);

    unsigned int* hp = &h[0][lane >> 2][0];
    unsigned int* ht = &h[1][lane >> 2][0];
    const unsigned int inc = 1u << ((lane & 3) * 8);

    for (int e = tid * 8; e < L; e += 8192) {   // one trip when L == 8192
        const int v = e >> 2;
        int4 pv0 = p4[v]; int4 pv1 = p4[v + 1];
        int4 tv0 = t4[v]; int4 tv1 = t4[v + 1];
        int4 mv0 = m4[v]; int4 mv1 = m4[v + 1];
        atomicAdd(hp + (mv0.x ? pv0.x : 0), inc);
        atomicAdd(ht + (mv0.x ? tv0.x : 0), inc);
        atomicAdd(hp + (mv0.y ? pv0.y : 0), inc);
        atomicAdd(ht + (mv0.y ? tv0.y : 0), inc);
        atomicAdd(hp + (mv0.z ? pv0.z : 0), inc);
        atomicAdd(ht + (mv0.z ? tv0.z : 0), inc);
        atomicAdd(hp + (mv0.w ? pv0.w : 0), inc);
        atomicAdd(ht + (mv0.w ? tv0.w : 0), inc);
        atomicAdd(hp + (mv1.x ? pv1.x : 0), inc);
        atomicAdd(ht + (mv1.x ? tv1.x : 0), inc);
        atomicAdd(hp + (mv1.y ? pv1.y : 0), inc);
        atomicAdd(ht + (mv1.y ? tv1.y : 0), inc);
        atomicAdd(hp + (mv1.z ? pv1.z : 0), inc);
        atomicAdd(ht + (mv1.z ? tv1.z : 0), inc);
        atomicAdd(hp + (mv1.w ? pv1.w : 0), inc);
        atomicAdd(ht + (mv1.w ? tv1.w : 0), inc);
    }
    __syncthreads();

    // ---- Phase 2: merge byte-counters; 130 threads (pred || targ) ----
    if (tid < 2 * N_CODONS) {
        const int which = (tid >= N_CODONS);
        const int bin   = tid - which * N_CODONS;
        unsigned int s = 0u;
#pragma unroll
        for (int g = 0; g < 16; ++g) {
            unsigned int w = h[which][g][bin];
            s += (w & 0x00FF00FFu) + ((w >> 8) & 0x00FF00FFu);
        }
        float f = (float)((s & 0xFFFFu) + (s >> 16));
        if (which) tr[bin] = f; else pr[bin] = f;
    }
    __syncthreads();

    // ---- Phases 3+4: RSCU, blend, normalize, KL — wave 0 only ----
    if (tid < 64) {
        // Per-AA totals: lane a<24 sums its codon range from LDS.
        float sumP = 0.f, sumT = 0.f;
        if (lane < N_AA) {
            int off = c_off[lane], sz = c_sz[lane];
            for (int k = 0; k < sz; ++k) {
                sumP += pr[off + k];
                sumT += tr[off + k];
            }
        }
        // Broadcast AA totals to codon lanes (per-lane src -> ds_bpermute).
        int aa = c_codon2aa[lane];
        float totP   = __shfl(sumP, aa, 64);
        float totT   = __shfl(sumT, aa, 64);
        float totP23 = __shfl(sumP, 23, 64);   // for bin 64 (AA 23)
        float totT23 = __shfl(sumT, 23, 64);

        float nsyn = c_nsyn[lane];
        float rscu_p = (totP > 0.f) ? pr[lane] * nsyn / fmaxf(totP, 1.f) : 0.f;
        float rscu_t = (totT > 0.f) ? tr[lane] * nsyn / fmaxf(totT, 1.f) : 0.f;
        float pe = rscu_p + 1e-8f;
        float te = 0.7f * rscu_t + 0.3f * rv + 1e-8f;

        float pe64 = 0.f, te64 = 0.f;
        if (lane == 0) {
            // bin 64: NSYN = 0 -> rscu terms are 0 regardless of counts
            // (c_nsyn[64] = 0), but keep the general form for clarity.
            float rp64 = (totP23 > 0.f) ? pr[64] * c_nsyn[64] / fmaxf(totP23, 1.f) : 0.f;
            float rt64 = (totT23 > 0.f) ? tr[64] * c_nsyn[64] / fmaxf(totT23, 1.f) : 0.f;
            pe64 = rp64 + 1e-8f;
            te64 = 0.7f * rt64 + 0.3f * rv64 + 1e-8f;
        }

        float psum = wave_sum64(pe + pe64);   // pe64 nonzero only on lane 0
        float tsum = wave_sum64(te + te64);
        float inv_ps = 1.f / psum;
        float inv_ts = 1.f / tsum;

        float tn = te * inv_ts;
        float pn = pe * inv_ps;
        float kl = tn * __logf(tn / pn);
        if (lane == 0) {
            float tn2 = te64 * inv_ts;
            float pn2 = pe64 * inv_ps;
            kl += tn2 * __logf(tn2 / pn2);
        }
        kl = wave_sum64(kl);
        if (lane == 0) out[b] = kl;
    }
}

extern "C" void kernel_launch(void* const* d_in, const int* in_sizes, int n_in,
                              void* d_out, int out_size, void* d_ws, size_t ws_size,
                              hipStream_t stream) {
    // setup_inputs order:
    // 0: pred_codon_ids (B,L) int32
    // 1: target_codon_ids (B,L) int32
    // 2: aa_ids (B,L) int32          -- unused (constant table instead)
    // 3: species_ids (B,) int32
    // 4: mask (B,L) bool -> promoted to int32 by harness
    // 5: ref_distributions (S,65) float32
    const int* pred    = (const int*)d_in[0];
    const int* targ    = (const int*)d_in[1];
    const int* species = (const int*)d_in[3];
    const int* mask    = (const int*)d_in[4];
    const float* ref   = (const float*)d_in[5];
    float* out         = (float*)d_out;

    const int B = in_sizes[3];
    const int L = in_sizes[0] / B;
    const int n_species = in_sizes[5] / N_CODONS;

    rscu_kl_kernel<<<dim3(B), dim3(1024), 0, stream>>>(
        pred, targ, mask, species, ref, out, L, n_species);
}